// Round 2
// baseline (210.092 us; speedup 1.0000x reference)
//
#include <hip/hip_runtime.h>

// Problem constants (from reference)
#define BATCH 2048
#define FDIM  1024
#define GTILE 16
#define F4    (FDIM / 4)          // 256 float4 col-groups per row
#define RA    8                   // rows per block in the stats kernels
#define NBLK  (BATCH / RA)        // 256 blocks -> one per CU

// ws layout (floats): colsum[1024] | ssum[1024] | sq[1024]   (zeroed each launch)
#define OFF_CS 0
#define OFF_S  1024
#define OFF_Q  2048

// Native vector type for nontemporal builtins (HIP_vector_type is rejected).
typedef float v4f __attribute__((ext_vector_type(4)));

// Pass 1: column sums of xf via global f32 atomics (256 contenders/address).
__global__ void __launch_bounds__(256) ka_colsum(const float4* __restrict__ xf,
                                                 float* __restrict__ colsum) {
    const int tid = threadIdx.x;              // col-group 0..255
    const int b   = blockIdx.x;               // row-chunk 0..255
    const float4* p = xf + (size_t)b * RA * F4 + tid;
    float4 s = {0.f, 0.f, 0.f, 0.f};
#pragma unroll
    for (int r = 0; r < RA; ++r) {
        float4 v = p[r * F4];
        s.x += v.x; s.y += v.y; s.z += v.z; s.w += v.w;
    }
    atomicAdd(&colsum[tid * 4 + 0], s.x);
    atomicAdd(&colsum[tid * 4 + 1], s.y);
    atomicAdd(&colsum[tid * 4 + 2], s.z);
    atomicAdd(&colsum[tid * 4 + 3], s.w);
}

// Pass 2: relu(x - mean) sum and sumsq. Mean comes straight from colsum (L2 hit).
__global__ void __launch_bounds__(256) kb_relustats(const float4* __restrict__ xf,
                                                    const float4* __restrict__ colsum4,
                                                    float* __restrict__ ssum,
                                                    float* __restrict__ sq) {
    const int tid = threadIdx.x;
    const int b   = blockIdx.x;
    const float inv_n = 1.0f / (float)BATCH;
    float4 m = colsum4[tid];
    m.x *= inv_n; m.y *= inv_n; m.z *= inv_n; m.w *= inv_n;

    const float4* p = xf + (size_t)b * RA * F4 + tid;
    float4 s = {0.f, 0.f, 0.f, 0.f};
    float4 q = {0.f, 0.f, 0.f, 0.f};
#pragma unroll
    for (int r = 0; r < RA; ++r) {
        float4 v = p[r * F4];
        float rx = fmaxf(v.x - m.x, 0.f);
        float ry = fmaxf(v.y - m.y, 0.f);
        float rz = fmaxf(v.z - m.z, 0.f);
        float rw = fmaxf(v.w - m.w, 0.f);
        s.x += rx; s.y += ry; s.z += rz; s.w += rw;
        q.x += rx * rx; q.y += ry * ry; q.z += rz * rz; q.w += rw * rw;
    }
    atomicAdd(&ssum[tid * 4 + 0], s.x);
    atomicAdd(&ssum[tid * 4 + 1], s.y);
    atomicAdd(&ssum[tid * 4 + 2], s.z);
    atomicAdd(&ssum[tid * 4 + 3], s.w);
    atomicAdd(&sq[tid * 4 + 0], q.x);
    atomicAdd(&sq[tid * 4 + 1], q.y);
    atomicAdd(&sq[tid * 4 + 2], q.z);
    atomicAdd(&sq[tid * 4 + 3], q.w);
}

// Pass 3: finalize (inlined, redundant per thread: 48 B of L2-hit loads + ~15 VALU ops)
// then stream the 16-way tiled output with non-temporal stores.
__global__ void __launch_bounds__(256) kd_write(const float4* __restrict__ xf,
                                                const float* __restrict__ wp,
                                                const float4* __restrict__ colsum4,
                                                const float4* __restrict__ ssum4,
                                                const float4* __restrict__ sq4,
                                                float4* __restrict__ out) {
    const int tid  = threadIdx.x;             // col-group 0..255
    const int row0 = blockIdx.x * 2;          // 2 rows per block
    const float inv_n  = 1.0f / (float)BATCH;
    const float inv_n1 = 1.0f / (float)(BATCH - 1);
    const float w = wp[0];

    float4 M = colsum4[tid];
    float4 S = ssum4[tid];
    float4 Q = sq4[tid];

    float4 m, scale, cc;
    float mu;
    m.x = M.x * inv_n;
    mu = S.x * inv_n; scale.x = w * rsqrtf((Q.x - S.x * mu) * inv_n1); cc.x = mu * scale.x;
    m.y = M.y * inv_n;
    mu = S.y * inv_n; scale.y = w * rsqrtf((Q.y - S.y * mu) * inv_n1); cc.y = mu * scale.y;
    m.z = M.z * inv_n;
    mu = S.z * inv_n; scale.z = w * rsqrtf((Q.z - S.z * mu) * inv_n1); cc.z = mu * scale.z;
    m.w = M.w * inv_n;
    mu = S.w * inv_n; scale.w = w * rsqrtf((Q.w - S.w * mu) * inv_n1); cc.w = mu * scale.w;

    float4 v0 = xf[(size_t)row0 * F4 + tid];
    float4 v1 = xf[(size_t)(row0 + 1) * F4 + tid];

    v4f o0, o1;
    o0.x = fmaxf(v0.x - m.x, 0.f) * scale.x - cc.x;
    o0.y = fmaxf(v0.y - m.y, 0.f) * scale.y - cc.y;
    o0.z = fmaxf(v0.z - m.z, 0.f) * scale.z - cc.z;
    o0.w = fmaxf(v0.w - m.w, 0.f) * scale.w - cc.w;
    o1.x = fmaxf(v1.x - m.x, 0.f) * scale.x - cc.x;
    o1.y = fmaxf(v1.y - m.y, 0.f) * scale.y - cc.y;
    o1.z = fmaxf(v1.z - m.z, 0.f) * scale.z - cc.z;
    o1.w = fmaxf(v1.w - m.w, 0.f) * scale.w - cc.w;

    v4f* dst0 = (v4f*)(out + (size_t)row0 * (GTILE * F4) + tid);
    v4f* dst1 = dst0 + (GTILE * F4);
#pragma unroll
    for (int g = 0; g < GTILE; ++g) {
        __builtin_nontemporal_store(o0, dst0 + g * F4);
        __builtin_nontemporal_store(o1, dst1 + g * F4);
    }
}

extern "C" void kernel_launch(void* const* d_in, const int* in_sizes, int n_in,
                              void* d_out, int out_size, void* d_ws, size_t ws_size,
                              hipStream_t stream) {
    const float4* xf4 = (const float4*)d_in[0];
    const float* wp   = (const float*)d_in[1];
    float* ws = (float*)d_ws;
    float* colsum = ws + OFF_CS;
    float* ssum   = ws + OFF_S;
    float* sq     = ws + OFF_Q;

    // 12 KB accumulator zero (ws is poisoned by the harness each iteration).
    (void)hipMemsetAsync(d_ws, 0, 3 * 1024 * sizeof(float), stream);

    ka_colsum<<<NBLK, 256, 0, stream>>>(xf4, colsum);
    kb_relustats<<<NBLK, 256, 0, stream>>>(xf4, (const float4*)colsum, ssum, sq);
    kd_write<<<BATCH / 2, 256, 0, stream>>>(xf4, wp, (const float4*)colsum,
                                            (const float4*)ssum, (const float4*)sq,
                                            (float4*)d_out);
}